// Round 21
// baseline (130.604 us; speedup 1.0000x reference)
//
#include <hip/hip_runtime.h>
#include <cmath>

#define N_   8
#define C_   64
#define H_   160
#define W_   160
#define HW_  25600
#define HH_  80
#define WH_  80
#define FSZ_ (N_ * C_ * HW_)   // 13,107,200
#define PSZ_ (N_ * HW_)        // 204,800

typedef unsigned short ushort8v __attribute__((ext_vector_type(8)));
typedef short          bf16x8  __attribute__((ext_vector_type(8)));
typedef float          f32x4   __attribute__((ext_vector_type(4)));

__device__ __forceinline__ float bf2f(unsigned short u) {
    return __uint_as_float(((unsigned)u) << 16);
}
__device__ __forceinline__ unsigned short f2bf(float f) {
    unsigned u = __float_as_uint(f);
    u += 0x7FFF + ((u >> 16) & 1);          // RNE
    return (unsigned short)(u >> 16);
}

// grid-sample setup: 4 tap indices + weights (align_corners=False, zeros pad)
__device__ __forceinline__ void gs_setup(float bgx, float bgy, float dx, float dy,
                                         int* idx, float* wgt)
{
    float px = ((bgx + dx * (1.f / 160.f)) + 1.f) * 80.f - 0.5f;
    float py = ((bgy + dy * (1.f / 160.f)) + 1.f) * 80.f - 0.5f;
    float x0f = floorf(px), y0f = floorf(py);
    float wx1 = px - x0f, wy1 = py - y0f, wx0 = 1.f - wx1, wy0 = 1.f - wy1;
    int x0 = (int)x0f, y0 = (int)y0f;
    float mx0 = ((unsigned)x0       < (unsigned)W_) ? 1.f : 0.f;
    float mx1 = ((unsigned)(x0 + 1) < (unsigned)W_) ? 1.f : 0.f;
    float my0 = ((unsigned)y0       < (unsigned)H_) ? 1.f : 0.f;
    float my1 = ((unsigned)(y0 + 1) < (unsigned)H_) ? 1.f : 0.f;
    int x0c = min(max(x0, 0), W_ - 1), x1c = min(max(x0 + 1, 0), W_ - 1);
    int y0c = min(max(y0, 0), H_ - 1), y1c = min(max(y0 + 1, 0), H_ - 1);
    idx[0] = y0c * W_ + x0c; wgt[0] = wy0 * wx0 * my0 * mx0;
    idx[1] = y0c * W_ + x1c; wgt[1] = wy0 * wx1 * my0 * mx1;
    idx[2] = y1c * W_ + x0c; wgt[2] = wy1 * wx0 * my1 * mx0;
    idx[3] = y1c * W_ + x1c; wgt[3] = wy1 * wx1 * my1 * mx1;
}

// -------- K0: compose d-branch weights AND pack all tables directly --------
__global__ __launch_bounds__(128) void compose_w_kernel(
    const float* __restrict__ w1a, const float* __restrict__ w1b,
    const float* __restrict__ s1, const float* __restrict__ b1,
    const float* __restrict__ m1, const float* __restrict__ v1,
    const float* __restrict__ s2, const float* __restrict__ b2,
    const float* __restrict__ m2, const float* __restrict__ v2,
    const float* __restrict__ w2a, const float* __restrict__ w2b,
    const float* __restrict__ ow,
    unsigned short* __restrict__ wAe, unsigned short* __restrict__ wOe,
    float* __restrict__ btap4)
{
    __shared__ float ws2[64], bpart[64];
    int bId = blockIdx.x;        // 36
    int row = bId / 9, tap = bId % 9;
    int br = row >> 1, oc = row & 1;
    int tid = threadIdx.x;       // 128

    const float* w1 = br ? w1b : w1a;
    const float* w2 = br ? w2b : w2a;

    if (tid < 64) {
        int mid = tid;
        float sc = br ? s2[mid] : s1[mid];
        float vv = br ? v2[mid] : v1[mid];
        float bb = br ? b2[mid] : b1[mid];
        float mm = br ? m2[mid] : m1[mid];
        float inv = sc * rsqrtf(vv + 1e-5f);
        float w2v = w2[oc * 576 + mid * 9 + tap];
        ws2[mid]   = w2v * inv;
        bpart[mid] = w2v * (bb - mm * inv);
    }
    __syncthreads();

    float sum = 0.f;
    #pragma unroll 8
    for (int mid = 0; mid < 64; ++mid)
        sum = fmaf(ws2[mid], w1[mid * 128 + tid], sum);
    {
        int s = tid >> 5, g = (tid >> 3) & 3, j = tid & 7;
        wAe[(tap * 4 + s) * 512 + (row + 16 * g) * 8 + j] = f2bf(sum);
    }
    if (row == 0) {
        for (int i = tid; i < 1536; i += 128) {
            int j = i & 7, k = i >> 3;
            int s = k / 48, k48 = k % 48;
            int g = k48 / 12, r16v = 4 + (k48 % 12);
            wAe[(tap * 4 + s) * 512 + (r16v + 16 * g) * 8 + j] = 0;
        }
    }
    if (row == 1) {
        for (int i = tid; i < 1024; i += 128) {
            int j = i & 7, lane = (i >> 3) & 63, s = i >> 9;
            int rowl = lane & 15;
            int ci = s * 32 + ((lane >> 4) & 3) * 8 + j;
            float v = (rowl == 0) ? ow[ci * 9 + tap] : 0.f;
            wOe[(tap * 2 + s) * 512 + lane * 8 + j] = f2bf(v);
        }
    }
    if (tid < 64) {
        float part = bpart[tid];
        #pragma unroll
        for (int off = 32; off > 0; off >>= 1)
            part += __shfl_down(part, off);
        if (tid == 0) btap4[tap * 4 + row] = part;
    }
}

// -------- K1: merged NCHW fp32 -> NHWC bf16 transpose (low + high_stage) ----
__global__ __launch_bounds__(256) void nchw_to_nhwc_merged(
    const float* __restrict__ low, const float* __restrict__ hs,
    unsigned short* __restrict__ lowb, unsigned short* __restrict__ hsb)
{
    int b = blockIdx.x;                 // 1000: 800 low + 200 hs
    const float* in;
    unsigned short* out;
    int hw, p;
    if (b < 800) { in = low; out = lowb; hw = HW_;       p = b * 256 + threadIdx.x; }
    else         { in = hs;  out = hsb;  hw = HH_ * WH_; p = (b - 800) * 256 + threadIdx.x; }
    int n = p / hw, rem = p % hw;
    const float* base = in + (long)n * 64 * hw + rem;
    unsigned o32[32];
    #pragma unroll
    for (int c2 = 0; c2 < 32; ++c2) {
        float v0 = base[(long)(2 * c2) * hw];
        float v1 = base[(long)(2 * c2 + 1) * hw];
        o32[c2] = (unsigned)f2bf(v0) | ((unsigned)f2bf(v1) << 16);
    }
    uint4* dst = reinterpret_cast<uint4*>(out + (long)p * 64);
    #pragma unroll
    for (int q = 0; q < 8; ++q)
        dst[q] = make_uint4(o32[q * 4], o32[q * 4 + 1], o32[q * 4 + 2], o32[q * 4 + 3]);
}

// -------- K2: bilinear resize 80->160 (align_corners=True) in NHWC bf16 -----
__global__ __launch_bounds__(256) void resize_high_nhwc(
    const unsigned short* __restrict__ hsb, unsigned short* __restrict__ highb)
{
    int p = blockIdx.x * 256 + threadIdx.x;
    int n = p / HW_, rem = p % HW_;
    int y = rem / W_, x = rem % W_;
    float sx = (x * 79.0f) / 159.0f;
    float sy = (y * 79.0f) / 159.0f;
    int ix0 = (int)sx, iy0 = (int)sy;
    float fx = sx - (float)ix0, fy = sy - (float)iy0;
    int ix1 = min(ix0 + 1, WH_ - 1), iy1 = min(iy0 + 1, HH_ - 1);
    long b = (long)n * (HH_ * WH_);
    const ushort8v* r00 = (const ushort8v*)(hsb + (b + iy0 * WH_ + ix0) * 64);
    const ushort8v* r01 = (const ushort8v*)(hsb + (b + iy0 * WH_ + ix1) * 64);
    const ushort8v* r10 = (const ushort8v*)(hsb + (b + iy1 * WH_ + ix0) * 64);
    const ushort8v* r11 = (const ushort8v*)(hsb + (b + iy1 * WH_ + ix1) * 64);
    float w00 = (1.f - fx) * (1.f - fy), w01 = fx * (1.f - fy);
    float w10 = (1.f - fx) * fy,         w11 = fx * fy;

    float acc[64];
    #pragma unroll
    for (int c = 0; c < 64; ++c) acc[c] = 0.f;
    #pragma unroll
    for (int q = 0; q < 8; ++q) {
        ushort8v v0 = r00[q], v1 = r01[q], v2 = r10[q], v3 = r11[q];
        #pragma unroll
        for (int j = 0; j < 8; ++j) {
            acc[q * 8 + j] = bf2f(v0[j]) * w00 + bf2f(v1[j]) * w01
                           + bf2f(v2[j]) * w10 + bf2f(v3[j]) * w11;
        }
    }
    unsigned o32[32];
    #pragma unroll
    for (int c2 = 0; c2 < 32; ++c2)
        o32[c2] = (unsigned)f2bf(acc[2 * c2]) | ((unsigned)f2bf(acc[2 * c2 + 1]) << 16);
    uint4* dst = reinterpret_cast<uint4*>(highb + (long)p * 64);
    #pragma unroll
    for (int q = 0; q < 8; ++q)
        dst[q] = make_uint4(o32[q * 4], o32[q * 4 + 1], o32[q * 4 + 2], o32[q * 4 + 3]);
}

// -------- K3: d1,d2 via COMPOSED conv3x3, LDS-tiled B + global A --------
__global__ __launch_bounds__(256) void d12_tiled_kernel(
    const unsigned short* __restrict__ lowb, const unsigned short* __restrict__ highb,
    const unsigned short* __restrict__ wAe, const float* __restrict__ btap4,
    float* __restrict__ d1, float* __restrict__ d2)
{
    __shared__ unsigned char lds[46080];   // 180 px * 256 B
    int b  = blockIdx.x;                  // 1600
    int n  = b / 200;
    int t  = b % 200;
    int ty = t / 10, tx = t % 10;         // 20 x 10 tiles of 8x16
    int y0 = ty * 8, x0 = tx * 16;
    int tid  = threadIdx.x;
    int lane = tid & 63;
    int wv   = tid >> 6;
    int r16  = lane & 15;
    int quad = lane >> 4;
    long nb = (long)n * HW_;

    for (int i = tid; i < 2880; i += 256) {
        int pix = i >> 4, qq = i & 15;
        int py = pix / 18, px = pix - py * 18;
        int gy = y0 + py - 1, gx = x0 + px - 1;
        bool valid = ((unsigned)gy < (unsigned)H_) && ((unsigned)gx < (unsigned)W_);
        ushort8v v = (ushort8v)0;
        if (valid) {
            const unsigned short* src = (qq < 8) ? lowb : highb;
            v = *reinterpret_cast<const ushort8v*>(
                src + ((long)(nb + gy * W_ + gx)) * 64 + (qq & 7) * 8);
        }
        *reinterpret_cast<ushort8v*>(
            lds + ((pix * 256 + qq * 16) ^ ((pix & 7) << 4))) = v;
    }
    __syncthreads();

    f32x4 accE[2], accO[2];
    accE[0] = accE[1] = accO[0] = accO[1] = (f32x4){0.f, 0.f, 0.f, 0.f};

    #pragma unroll
    for (int kx = 0; kx < 3; ++kx) {
        #pragma unroll
        for (int s = 0; s < 4; ++s) {
            bf16x8 Br[4];
            #pragma unroll
            for (int r = 0; r < 4; ++r) {
                int pix = (wv * 2 + r) * 18 + r16 + kx;
                Br[r] = *reinterpret_cast<const bf16x8*>(
                    lds + ((pix * 256 + s * 64 + quad * 16) ^ ((pix & 7) << 4)));
            }
            #pragma unroll
            for (int ky = 0; ky < 3; ++ky) {
                int tap = ky * 3 + kx;
                bf16x8 A = *reinterpret_cast<const bf16x8*>(
                    wAe + (tap * 4 + s) * 512 + lane * 8);
                if ((tap ^ s) & 1) {
                    accO[0] = __builtin_amdgcn_mfma_f32_16x16x32_bf16(A, Br[ky],     accO[0], 0, 0, 0);
                    accO[1] = __builtin_amdgcn_mfma_f32_16x16x32_bf16(A, Br[ky + 1], accO[1], 0, 0, 0);
                } else {
                    accE[0] = __builtin_amdgcn_mfma_f32_16x16x32_bf16(A, Br[ky],     accE[0], 0, 0, 0);
                    accE[1] = __builtin_amdgcn_mfma_f32_16x16x32_bf16(A, Br[ky + 1], accE[1], 0, 0, 0);
                }
            }
        }
    }

    #pragma unroll
    for (int g = 0; g < 2; ++g) {
        int yg = y0 + wv * 2 + g;
        int x  = x0 + r16;
        bool interior = (yg > 0) && (yg < H_ - 1) && (x0 > 0) && (x0 + 16 < W_);
        float b0 = 0.f, b1v = 0.f, b2v = 0.f, b3 = 0.f;
        #pragma unroll
        for (int tap = 0; tap < 9; ++tap) {
            int ky = tap / 3 - 1, kx = tap % 3 - 1;
            float m = 1.f;
            if (!interior) {
                int yy = yg + ky, xx = x + kx;
                m = (((unsigned)yy < (unsigned)H_) && ((unsigned)xx < (unsigned)W_))
                  ? 1.f : 0.f;
            }
            const float4 bt = *reinterpret_cast<const float4*>(btap4 + tap * 4);
            b0  = fmaf(m, bt.x, b0);
            b1v = fmaf(m, bt.y, b1v);
            b2v = fmaf(m, bt.z, b2v);
            b3  = fmaf(m, bt.w, b3);
        }
        if (quad == 0) {
            long p = nb + (long)yg * W_ + x;
            *reinterpret_cast<float2*>(d1 + p * 2) =
                make_float2(accE[g][0] + accO[g][0] + b0,
                            accE[g][1] + accO[g][1] + b1v);
            *reinterpret_cast<float2*>(d2 + p * 2) =
                make_float2(accE[g][2] + accO[g][2] + b2v,
                            accE[g][3] + accO[g][3] + b3);
        }
    }
}

// -------- K4: FUSED warp+combine -> f + LDS, then out conv3x3 via MFMA ------
// Tile 16x16 output, halo 18x18 = 324 px. 512 threads (8 waves).
// Phase 1: 648 (px, half=32ch) self-contained gather units (R19 dataflow,
//          2x wider units -> setup duplicated 2x instead of 4x).
// Phase 2: out conv via MFMA.
__global__ __launch_bounds__(512) void warp_out_fused(
    const unsigned short* __restrict__ lowb, const unsigned short* __restrict__ highb,
    const float* __restrict__ d1, const float* __restrict__ d2,
    const float* __restrict__ imin, const float* __restrict__ gamma,
    const unsigned short* __restrict__ wOe, const float* __restrict__ ob,
    float* __restrict__ f, float* __restrict__ o)
{
    __shared__ unsigned char lds[41472];   // 324 px * 128 B
    int b  = blockIdx.x;                  // 800
    int n  = b / 100;
    int t  = b % 100;
    int ty = t / 10, tx = t % 10;
    int y0 = ty * 16, x0 = tx * 16;
    int tid  = threadIdx.x;
    long nb = (long)n * HW_;
    float gm = gamma[0];

    // ---- phase 1: 648 units (324 px x 2 halves) ----
    for (int u = tid; u < 648; u += 512) {
        int pix = u >> 1, half = u & 1;
        int py = pix / 18, px = pix - py * 18;
        int gy = y0 + py - 1, gx = x0 + px - 1;
        bool valid = ((unsigned)gy < (unsigned)H_) && ((unsigned)gx < (unsigned)W_);

        unsigned o32[16];
        #pragma unroll
        for (int k = 0; k < 16; ++k) o32[k] = 0;

        if (valid) {
            int pp = gy * W_ + gx;
            long p = nb + pp;

            float bgx = -1.f + gx * (2.f / 159.f);
            float bgy = -1.f + gy * (2.f / 159.f);
            float2 dv1 = *reinterpret_cast<const float2*>(d1 + p * 2);
            float2 dv2 = *reinterpret_cast<const float2*>(d2 + p * 2);

            int idx1[4], idx2[4];
            float wgt1[4], wgt2[4];
            gs_setup(bgx, bgy, dv1.x, dv1.y, idx1, wgt1);
            gs_setup(bgx, bgy, dv2.x, dv2.y, idx2, wgt2);

            float s;
            {
                float sx = (gx * 79.0f) / 159.0f;
                float sy = (gy * 79.0f) / 159.0f;
                int ix0 = (int)sx, iy0 = (int)sy;
                float fx = sx - (float)ix0, fy = sy - (float)iy0;
                int ix1 = min(ix0 + 1, WH_ - 1), iy1 = min(iy0 + 1, HH_ - 1);
                const float* ip = imin + n * (HH_ * WH_);
                float v00 = ip[iy0 * WH_ + ix0], v01 = ip[iy0 * WH_ + ix1];
                float v10 = ip[iy1 * WH_ + ix0], v11 = ip[iy1 * WH_ + ix1];
                float v = (v00 * (1.f - fx) + v01 * fx) * (1.f - fy)
                        + (v10 * (1.f - fx) + v11 * fx) * fy;
                s = 1.f + gm * (1.f / (1.f + expf(-v)));
            }

            float acc[32];
            #pragma unroll
            for (int c = 0; c < 32; ++c) acc[c] = 0.f;

            #pragma unroll
            for (int j = 0; j < 4; ++j) {
                const ushort8v* row = (const ushort8v*)(
                    highb + (nb + idx1[j]) * 64 + half * 32);
                float w = wgt1[j];
                #pragma unroll
                for (int q = 0; q < 4; ++q) {
                    ushort8v v = row[q];
                    #pragma unroll
                    for (int k = 0; k < 8; ++k)
                        acc[q * 8 + k] = fmaf(bf2f(v[k]), w, acc[q * 8 + k]);
                }
            }
            #pragma unroll
            for (int j = 0; j < 4; ++j) {
                const ushort8v* row = (const ushort8v*)(
                    lowb + (nb + idx2[j]) * 64 + half * 32);
                float w = wgt2[j];
                #pragma unroll
                for (int q = 0; q < 4; ++q) {
                    ushort8v v = row[q];
                    #pragma unroll
                    for (int k = 0; k < 8; ++k)
                        acc[q * 8 + k] = fmaf(bf2f(v[k]), w, acc[q * 8 + k]);
                }
            }

            bool interior = (py >= 1) && (py <= 16) && (px >= 1) && (px <= 16);
            float* fp = f + ((long)n * 64 + half * 32) * HW_ + pp;
            #pragma unroll
            for (int c2 = 0; c2 < 16; ++c2) {
                float f0 = acc[2 * c2]     * s;
                float f1 = acc[2 * c2 + 1] * s;
                if (interior) {
                    fp[(long)(2 * c2) * HW_]     = f0;
                    fp[(long)(2 * c2 + 1) * HW_] = f1;
                }
                o32[c2] = (unsigned)f2bf(f0) | ((unsigned)f2bf(f1) << 16);
            }
        }

        int base = pix * 128 + half * 64;
        int sw   = (pix & 7) << 4;
        #pragma unroll
        for (int k4 = 0; k4 < 4; ++k4) {
            *reinterpret_cast<uint4*>(lds + ((base + k4 * 16) ^ sw)) =
                make_uint4(o32[k4 * 4], o32[k4 * 4 + 1],
                           o32[k4 * 4 + 2], o32[k4 * 4 + 3]);
        }
    }
    __syncthreads();

    // ---- phase 2: out conv via MFMA; wave wv owns rows 2wv, 2wv+1 ----
    int lane = tid & 63;
    int wv   = tid >> 6;
    int r16  = lane & 15;
    int quad = lane >> 4;

    f32x4 accE[2], accO[2];
    accE[0] = accE[1] = accO[0] = accO[1] = (f32x4){0.f, 0.f, 0.f, 0.f};

    #pragma unroll
    for (int kx = 0; kx < 3; ++kx) {
        #pragma unroll
        for (int s = 0; s < 2; ++s) {
            bf16x8 Br[4];
            #pragma unroll
            for (int r = 0; r < 4; ++r) {
                int pix = (wv * 2 + r) * 18 + r16 + kx;
                Br[r] = *reinterpret_cast<const bf16x8*>(
                    lds + ((pix * 128 + s * 64 + quad * 16) ^ ((pix & 7) << 4)));
            }
            #pragma unroll
            for (int ky = 0; ky < 3; ++ky) {
                int tap = ky * 3 + kx;
                bf16x8 A = *reinterpret_cast<const bf16x8*>(
                    wOe + (tap * 2 + s) * 512 + lane * 8);
                if ((tap ^ s) & 1) {
                    accO[0] = __builtin_amdgcn_mfma_f32_16x16x32_bf16(A, Br[ky],     accO[0], 0, 0, 0);
                    accO[1] = __builtin_amdgcn_mfma_f32_16x16x32_bf16(A, Br[ky + 1], accO[1], 0, 0, 0);
                } else {
                    accE[0] = __builtin_amdgcn_mfma_f32_16x16x32_bf16(A, Br[ky],     accE[0], 0, 0, 0);
                    accE[1] = __builtin_amdgcn_mfma_f32_16x16x32_bf16(A, Br[ky + 1], accE[1], 0, 0, 0);
                }
            }
        }
    }

    if (quad == 0) {
        float bias = ob[0];
        #pragma unroll
        for (int g = 0; g < 2; ++g) {
            int yg = y0 + wv * 2 + g;
            o[nb + (long)yg * W_ + x0 + r16] = accE[g][0] + accO[g][0] + bias;
        }
    }
}

extern "C" void kernel_launch(void* const* d_in, const int* in_sizes, int n_in,
                              void* d_out, int out_size, void* d_ws, size_t ws_size,
                              hipStream_t stream) {
    const float* low    = (const float*)d_in[0];
    const float* hsin   = (const float*)d_in[1];
    const float* imin   = (const float*)d_in[2];
    const float* dg1_w1 = (const float*)d_in[3];
    const float* dg1_s  = (const float*)d_in[4];
    const float* dg1_b  = (const float*)d_in[5];
    const float* dg1_m  = (const float*)d_in[6];
    const float* dg1_v  = (const float*)d_in[7];
    const float* dg1_w2 = (const float*)d_in[8];
    const float* dg2_w1 = (const float*)d_in[9];
    const float* dg2_s  = (const float*)d_in[10];
    const float* dg2_b  = (const float*)d_in[11];
    const float* dg2_m  = (const float*)d_in[12];
    const float* dg2_v  = (const float*)d_in[13];
    const float* dg2_w2 = (const float*)d_in[14];
    const float* gamma  = (const float*)d_in[15];
    const float* out_w  = (const float*)d_in[16];
    const float* out_b  = (const float*)d_in[17];

    float* ws    = (float*)d_ws;
    float* d1    = ws;                          // 2*PSZ_
    float* d2    = d1 + 2 * PSZ_;               // 2*PSZ_
    float* btap4 = d2 + 2 * PSZ_;               // 40
    unsigned short* wAe   = (unsigned short*)(btap4 + 40);   // 18432
    unsigned short* wOe   = wAe + 18432;        // 9216
    unsigned short* lowb  = wOe + 9216;         // FSZ_ bf16 NHWC
    unsigned short* highb = lowb + FSZ_;        // FSZ_ bf16 NHWC
    unsigned short* hsb   = highb + FSZ_;       // N*HH*WH*64 bf16 NHWC

    float* fout = (float*)d_out;                // FSZ_ (output 0, NCHW fp32)
    float* oout = fout + FSZ_;                  // PSZ_ (output 1)

    compose_w_kernel<<<36, 128, 0, stream>>>(
        dg1_w1, dg2_w1, dg1_s, dg1_b, dg1_m, dg1_v,
        dg2_s, dg2_b, dg2_m, dg2_v, dg1_w2, dg2_w2, out_w,
        wAe, wOe, btap4);
    nchw_to_nhwc_merged<<<1000, 256, 0, stream>>>(low, hsin, lowb, hsb);
    resize_high_nhwc<<<PSZ_ / 256, 256, 0, stream>>>(hsb, highb);
    d12_tiled_kernel<<<1600, 256, 0, stream>>>(
        lowb, highb, wAe, btap4, d1, d2);
    warp_out_fused<<<800, 512, 0, stream>>>(
        lowb, highb, d1, d2, imin, gamma, wOe, out_b, fout, oout);
}

// Round 22
// 119.822 us; speedup vs baseline: 1.0900x; 1.0900x over previous
//
#include <hip/hip_runtime.h>
#include <cmath>

#define N_   8
#define C_   64
#define H_   160
#define W_   160
#define HW_  25600
#define HH_  80
#define WH_  80
#define FSZ_ (N_ * C_ * HW_)   // 13,107,200
#define PSZ_ (N_ * HW_)        // 204,800

typedef unsigned short ushort8v __attribute__((ext_vector_type(8)));
typedef short          bf16x8  __attribute__((ext_vector_type(8)));
typedef float          f32x4   __attribute__((ext_vector_type(4)));

__device__ __forceinline__ float bf2f(unsigned short u) {
    return __uint_as_float(((unsigned)u) << 16);
}
__device__ __forceinline__ unsigned short f2bf(float f) {
    unsigned u = __float_as_uint(f);
    u += 0x7FFF + ((u >> 16) & 1);          // RNE
    return (unsigned short)(u >> 16);
}

// grid-sample setup: 4 tap indices + weights (align_corners=False, zeros pad)
__device__ __forceinline__ void gs_setup(float bgx, float bgy, float dx, float dy,
                                         int* idx, float* wgt)
{
    float px = ((bgx + dx * (1.f / 160.f)) + 1.f) * 80.f - 0.5f;
    float py = ((bgy + dy * (1.f / 160.f)) + 1.f) * 80.f - 0.5f;
    float x0f = floorf(px), y0f = floorf(py);
    float wx1 = px - x0f, wy1 = py - y0f, wx0 = 1.f - wx1, wy0 = 1.f - wy1;
    int x0 = (int)x0f, y0 = (int)y0f;
    float mx0 = ((unsigned)x0       < (unsigned)W_) ? 1.f : 0.f;
    float mx1 = ((unsigned)(x0 + 1) < (unsigned)W_) ? 1.f : 0.f;
    float my0 = ((unsigned)y0       < (unsigned)H_) ? 1.f : 0.f;
    float my1 = ((unsigned)(y0 + 1) < (unsigned)H_) ? 1.f : 0.f;
    int x0c = min(max(x0, 0), W_ - 1), x1c = min(max(x0 + 1, 0), W_ - 1);
    int y0c = min(max(y0, 0), H_ - 1), y1c = min(max(y0 + 1, 0), H_ - 1);
    idx[0] = y0c * W_ + x0c; wgt[0] = wy0 * wx0 * my0 * mx0;
    idx[1] = y0c * W_ + x1c; wgt[1] = wy0 * wx1 * my0 * mx1;
    idx[2] = y1c * W_ + x0c; wgt[2] = wy1 * wx0 * my1 * mx0;
    idx[3] = y1c * W_ + x1c; wgt[3] = wy1 * wx1 * my1 * mx1;
}

// -------- K0: compose d-branch weights AND pack all tables directly --------
__global__ __launch_bounds__(128) void compose_w_kernel(
    const float* __restrict__ w1a, const float* __restrict__ w1b,
    const float* __restrict__ s1, const float* __restrict__ b1,
    const float* __restrict__ m1, const float* __restrict__ v1,
    const float* __restrict__ s2, const float* __restrict__ b2,
    const float* __restrict__ m2, const float* __restrict__ v2,
    const float* __restrict__ w2a, const float* __restrict__ w2b,
    const float* __restrict__ ow,
    unsigned short* __restrict__ wAe, unsigned short* __restrict__ wOe,
    float* __restrict__ btap4)
{
    __shared__ float ws2[64], bpart[64];
    int bId = blockIdx.x;        // 36
    int row = bId / 9, tap = bId % 9;
    int br = row >> 1, oc = row & 1;
    int tid = threadIdx.x;       // 128

    const float* w1 = br ? w1b : w1a;
    const float* w2 = br ? w2b : w2a;

    if (tid < 64) {
        int mid = tid;
        float sc = br ? s2[mid] : s1[mid];
        float vv = br ? v2[mid] : v1[mid];
        float bb = br ? b2[mid] : b1[mid];
        float mm = br ? m2[mid] : m1[mid];
        float inv = sc * rsqrtf(vv + 1e-5f);
        float w2v = w2[oc * 576 + mid * 9 + tap];
        ws2[mid]   = w2v * inv;
        bpart[mid] = w2v * (bb - mm * inv);
    }
    __syncthreads();

    float sum = 0.f;
    #pragma unroll 8
    for (int mid = 0; mid < 64; ++mid)
        sum = fmaf(ws2[mid], w1[mid * 128 + tid], sum);
    {
        int s = tid >> 5, g = (tid >> 3) & 3, j = tid & 7;
        wAe[(tap * 4 + s) * 512 + (row + 16 * g) * 8 + j] = f2bf(sum);
    }
    if (row == 0) {
        for (int i = tid; i < 1536; i += 128) {
            int j = i & 7, k = i >> 3;
            int s = k / 48, k48 = k % 48;
            int g = k48 / 12, r16v = 4 + (k48 % 12);
            wAe[(tap * 4 + s) * 512 + (r16v + 16 * g) * 8 + j] = 0;
        }
    }
    if (row == 1) {
        for (int i = tid; i < 1024; i += 128) {
            int j = i & 7, lane = (i >> 3) & 63, s = i >> 9;
            int rowl = lane & 15;
            int ci = s * 32 + ((lane >> 4) & 3) * 8 + j;
            float v = (rowl == 0) ? ow[ci * 9 + tap] : 0.f;
            wOe[(tap * 2 + s) * 512 + lane * 8 + j] = f2bf(v);
        }
    }
    if (tid < 64) {
        float part = bpart[tid];
        #pragma unroll
        for (int off = 32; off > 0; off >>= 1)
            part += __shfl_down(part, off);
        if (tid == 0) btap4[tap * 4 + row] = part;
    }
}

// -------- K1: merged NCHW fp32 -> NHWC bf16 transpose (low + high_stage) ----
__global__ __launch_bounds__(256) void nchw_to_nhwc_merged(
    const float* __restrict__ low, const float* __restrict__ hs,
    unsigned short* __restrict__ lowb, unsigned short* __restrict__ hsb)
{
    int b = blockIdx.x;                 // 1000: 800 low + 200 hs
    const float* in;
    unsigned short* out;
    int hw, p;
    if (b < 800) { in = low; out = lowb; hw = HW_;       p = b * 256 + threadIdx.x; }
    else         { in = hs;  out = hsb;  hw = HH_ * WH_; p = (b - 800) * 256 + threadIdx.x; }
    int n = p / hw, rem = p % hw;
    const float* base = in + (long)n * 64 * hw + rem;
    unsigned o32[32];
    #pragma unroll
    for (int c2 = 0; c2 < 32; ++c2) {
        float v0 = base[(long)(2 * c2) * hw];
        float v1 = base[(long)(2 * c2 + 1) * hw];
        o32[c2] = (unsigned)f2bf(v0) | ((unsigned)f2bf(v1) << 16);
    }
    uint4* dst = reinterpret_cast<uint4*>(out + (long)p * 64);
    #pragma unroll
    for (int q = 0; q < 8; ++q)
        dst[q] = make_uint4(o32[q * 4], o32[q * 4 + 1], o32[q * 4 + 2], o32[q * 4 + 3]);
}

// -------- K2: bilinear resize 80->160 (align_corners=True) in NHWC bf16 -----
__global__ __launch_bounds__(256) void resize_high_nhwc(
    const unsigned short* __restrict__ hsb, unsigned short* __restrict__ highb)
{
    int p = blockIdx.x * 256 + threadIdx.x;
    int n = p / HW_, rem = p % HW_;
    int y = rem / W_, x = rem % W_;
    float sx = (x * 79.0f) / 159.0f;
    float sy = (y * 79.0f) / 159.0f;
    int ix0 = (int)sx, iy0 = (int)sy;
    float fx = sx - (float)ix0, fy = sy - (float)iy0;
    int ix1 = min(ix0 + 1, WH_ - 1), iy1 = min(iy0 + 1, HH_ - 1);
    long b = (long)n * (HH_ * WH_);
    const ushort8v* r00 = (const ushort8v*)(hsb + (b + iy0 * WH_ + ix0) * 64);
    const ushort8v* r01 = (const ushort8v*)(hsb + (b + iy0 * WH_ + ix1) * 64);
    const ushort8v* r10 = (const ushort8v*)(hsb + (b + iy1 * WH_ + ix0) * 64);
    const ushort8v* r11 = (const ushort8v*)(hsb + (b + iy1 * WH_ + ix1) * 64);
    float w00 = (1.f - fx) * (1.f - fy), w01 = fx * (1.f - fy);
    float w10 = (1.f - fx) * fy,         w11 = fx * fy;

    float acc[64];
    #pragma unroll
    for (int c = 0; c < 64; ++c) acc[c] = 0.f;
    #pragma unroll
    for (int q = 0; q < 8; ++q) {
        ushort8v v0 = r00[q], v1 = r01[q], v2 = r10[q], v3 = r11[q];
        #pragma unroll
        for (int j = 0; j < 8; ++j) {
            acc[q * 8 + j] = bf2f(v0[j]) * w00 + bf2f(v1[j]) * w01
                           + bf2f(v2[j]) * w10 + bf2f(v3[j]) * w11;
        }
    }
    unsigned o32[32];
    #pragma unroll
    for (int c2 = 0; c2 < 32; ++c2)
        o32[c2] = (unsigned)f2bf(acc[2 * c2]) | ((unsigned)f2bf(acc[2 * c2 + 1]) << 16);
    uint4* dst = reinterpret_cast<uint4*>(highb + (long)p * 64);
    #pragma unroll
    for (int q = 0; q < 8; ++q)
        dst[q] = make_uint4(o32[q * 4], o32[q * 4 + 1], o32[q * 4 + 2], o32[q * 4 + 3]);
}

// -------- K3: d1,d2 via COMPOSED conv3x3, LDS-tiled B + global A --------
__global__ __launch_bounds__(256) void d12_tiled_kernel(
    const unsigned short* __restrict__ lowb, const unsigned short* __restrict__ highb,
    const unsigned short* __restrict__ wAe, const float* __restrict__ btap4,
    float* __restrict__ d1, float* __restrict__ d2)
{
    __shared__ unsigned char lds[46080];   // 180 px * 256 B
    int b  = blockIdx.x;                  // 1600
    int n  = b / 200;
    int t  = b % 200;
    int ty = t / 10, tx = t % 10;         // 20 x 10 tiles of 8x16
    int y0 = ty * 8, x0 = tx * 16;
    int tid  = threadIdx.x;
    int lane = tid & 63;
    int wv   = tid >> 6;
    int r16  = lane & 15;
    int quad = lane >> 4;
    long nb = (long)n * HW_;

    for (int i = tid; i < 2880; i += 256) {
        int pix = i >> 4, qq = i & 15;
        int py = pix / 18, px = pix - py * 18;
        int gy = y0 + py - 1, gx = x0 + px - 1;
        bool valid = ((unsigned)gy < (unsigned)H_) && ((unsigned)gx < (unsigned)W_);
        ushort8v v = (ushort8v)0;
        if (valid) {
            const unsigned short* src = (qq < 8) ? lowb : highb;
            v = *reinterpret_cast<const ushort8v*>(
                src + ((long)(nb + gy * W_ + gx)) * 64 + (qq & 7) * 8);
        }
        *reinterpret_cast<ushort8v*>(
            lds + ((pix * 256 + qq * 16) ^ ((pix & 7) << 4))) = v;
    }
    __syncthreads();

    f32x4 accE[2], accO[2];
    accE[0] = accE[1] = accO[0] = accO[1] = (f32x4){0.f, 0.f, 0.f, 0.f};

    #pragma unroll
    for (int kx = 0; kx < 3; ++kx) {
        #pragma unroll
        for (int s = 0; s < 4; ++s) {
            bf16x8 Br[4];
            #pragma unroll
            for (int r = 0; r < 4; ++r) {
                int pix = (wv * 2 + r) * 18 + r16 + kx;
                Br[r] = *reinterpret_cast<const bf16x8*>(
                    lds + ((pix * 256 + s * 64 + quad * 16) ^ ((pix & 7) << 4)));
            }
            #pragma unroll
            for (int ky = 0; ky < 3; ++ky) {
                int tap = ky * 3 + kx;
                bf16x8 A = *reinterpret_cast<const bf16x8*>(
                    wAe + (tap * 4 + s) * 512 + lane * 8);
                if ((tap ^ s) & 1) {
                    accO[0] = __builtin_amdgcn_mfma_f32_16x16x32_bf16(A, Br[ky],     accO[0], 0, 0, 0);
                    accO[1] = __builtin_amdgcn_mfma_f32_16x16x32_bf16(A, Br[ky + 1], accO[1], 0, 0, 0);
                } else {
                    accE[0] = __builtin_amdgcn_mfma_f32_16x16x32_bf16(A, Br[ky],     accE[0], 0, 0, 0);
                    accE[1] = __builtin_amdgcn_mfma_f32_16x16x32_bf16(A, Br[ky + 1], accE[1], 0, 0, 0);
                }
            }
        }
    }

    #pragma unroll
    for (int g = 0; g < 2; ++g) {
        int yg = y0 + wv * 2 + g;
        int x  = x0 + r16;
        bool interior = (yg > 0) && (yg < H_ - 1) && (x0 > 0) && (x0 + 16 < W_);
        float b0 = 0.f, b1v = 0.f, b2v = 0.f, b3 = 0.f;
        #pragma unroll
        for (int tap = 0; tap < 9; ++tap) {
            int ky = tap / 3 - 1, kx = tap % 3 - 1;
            float m = 1.f;
            if (!interior) {
                int yy = yg + ky, xx = x + kx;
                m = (((unsigned)yy < (unsigned)H_) && ((unsigned)xx < (unsigned)W_))
                  ? 1.f : 0.f;
            }
            const float4 bt = *reinterpret_cast<const float4*>(btap4 + tap * 4);
            b0  = fmaf(m, bt.x, b0);
            b1v = fmaf(m, bt.y, b1v);
            b2v = fmaf(m, bt.z, b2v);
            b3  = fmaf(m, bt.w, b3);
        }
        if (quad == 0) {
            long p = nb + (long)yg * W_ + x;
            *reinterpret_cast<float2*>(d1 + p * 2) =
                make_float2(accE[g][0] + accO[g][0] + b0,
                            accE[g][1] + accO[g][1] + b1v);
            *reinterpret_cast<float2*>(d2 + p * 2) =
                make_float2(accE[g][2] + accO[g][2] + b2v,
                            accE[g][3] + accO[g][3] + b3);
        }
    }
}

// -------- K4: FUSED warp+combine -> f + LDS, then out conv3x3 via MFMA ------
// Tile 16x16 output, halo 18x18 = 324 px. 512 threads (8 waves).
__global__ __launch_bounds__(512) void warp_out_fused(
    const unsigned short* __restrict__ lowb, const unsigned short* __restrict__ highb,
    const float* __restrict__ d1, const float* __restrict__ d2,
    const float* __restrict__ imin, const float* __restrict__ gamma,
    const unsigned short* __restrict__ wOe, const float* __restrict__ ob,
    float* __restrict__ f, float* __restrict__ o)
{
    __shared__ unsigned char lds[41472];   // 324 px * 128 B
    int b  = blockIdx.x;                  // 800
    int n  = b / 100;
    int t  = b % 100;
    int ty = t / 10, tx = t % 10;
    int y0 = ty * 16, x0 = tx * 16;
    int tid  = threadIdx.x;
    long nb = (long)n * HW_;
    float gm = gamma[0];

    // ---- phase 1: 1296 units (324 px x 4 quarters) ----
    for (int u = tid; u < 1296; u += 512) {
        int pix = u >> 2, quarter = u & 3;
        int py = pix / 18, px = pix - py * 18;
        int gy = y0 + py - 1, gx = x0 + px - 1;
        bool valid = ((unsigned)gy < (unsigned)H_) && ((unsigned)gx < (unsigned)W_);

        unsigned o32[8];
        #pragma unroll
        for (int k = 0; k < 8; ++k) o32[k] = 0;

        if (valid) {
            int pp = gy * W_ + gx;
            long p = nb + pp;

            float bgx = -1.f + gx * (2.f / 159.f);
            float bgy = -1.f + gy * (2.f / 159.f);
            float2 dv1 = *reinterpret_cast<const float2*>(d1 + p * 2);
            float2 dv2 = *reinterpret_cast<const float2*>(d2 + p * 2);

            int idx1[4], idx2[4];
            float wgt1[4], wgt2[4];
            gs_setup(bgx, bgy, dv1.x, dv1.y, idx1, wgt1);
            gs_setup(bgx, bgy, dv2.x, dv2.y, idx2, wgt2);

            float s;
            {
                float sx = (gx * 79.0f) / 159.0f;
                float sy = (gy * 79.0f) / 159.0f;
                int ix0 = (int)sx, iy0 = (int)sy;
                float fx = sx - (float)ix0, fy = sy - (float)iy0;
                int ix1 = min(ix0 + 1, WH_ - 1), iy1 = min(iy0 + 1, HH_ - 1);
                const float* ip = imin + n * (HH_ * WH_);
                float v00 = ip[iy0 * WH_ + ix0], v01 = ip[iy0 * WH_ + ix1];
                float v10 = ip[iy1 * WH_ + ix0], v11 = ip[iy1 * WH_ + ix1];
                float v = (v00 * (1.f - fx) + v01 * fx) * (1.f - fy)
                        + (v10 * (1.f - fx) + v11 * fx) * fy;
                s = 1.f + gm * (1.f / (1.f + expf(-v)));
            }

            float acc[16];
            #pragma unroll
            for (int c = 0; c < 16; ++c) acc[c] = 0.f;

            #pragma unroll
            for (int j = 0; j < 4; ++j) {
                const ushort8v* row = (const ushort8v*)(
                    highb + (nb + idx1[j]) * 64 + quarter * 16);
                float w = wgt1[j];
                #pragma unroll
                for (int q = 0; q < 2; ++q) {
                    ushort8v v = row[q];
                    #pragma unroll
                    for (int k = 0; k < 8; ++k)
                        acc[q * 8 + k] = fmaf(bf2f(v[k]), w, acc[q * 8 + k]);
                }
            }
            #pragma unroll
            for (int j = 0; j < 4; ++j) {
                const ushort8v* row = (const ushort8v*)(
                    lowb + (nb + idx2[j]) * 64 + quarter * 16);
                float w = wgt2[j];
                #pragma unroll
                for (int q = 0; q < 2; ++q) {
                    ushort8v v = row[q];
                    #pragma unroll
                    for (int k = 0; k < 8; ++k)
                        acc[q * 8 + k] = fmaf(bf2f(v[k]), w, acc[q * 8 + k]);
                }
            }

            bool interior = (py >= 1) && (py <= 16) && (px >= 1) && (px <= 16);
            float* fp = f + ((long)n * 64 + quarter * 16) * HW_ + pp;
            #pragma unroll
            for (int c2 = 0; c2 < 8; ++c2) {
                float f0 = acc[2 * c2]     * s;
                float f1 = acc[2 * c2 + 1] * s;
                if (interior) {
                    fp[(long)(2 * c2) * HW_]     = f0;
                    fp[(long)(2 * c2 + 1) * HW_] = f1;
                }
                o32[c2] = (unsigned)f2bf(f0) | ((unsigned)f2bf(f1) << 16);
            }
        }

        int base = pix * 128 + quarter * 32;
        int sw   = (pix & 7) << 4;
        *reinterpret_cast<uint4*>(lds + ((base) ^ sw)) =
            make_uint4(o32[0], o32[1], o32[2], o32[3]);
        *reinterpret_cast<uint4*>(lds + ((base + 16) ^ sw)) =
            make_uint4(o32[4], o32[5], o32[6], o32[7]);
    }
    __syncthreads();

    // ---- phase 2: out conv via MFMA; wave wv owns rows 2wv, 2wv+1 ----
    int lane = tid & 63;
    int wv   = tid >> 6;
    int r16  = lane & 15;
    int quad = lane >> 4;

    f32x4 accE[2], accO[2];
    accE[0] = accE[1] = accO[0] = accO[1] = (f32x4){0.f, 0.f, 0.f, 0.f};

    #pragma unroll
    for (int kx = 0; kx < 3; ++kx) {
        #pragma unroll
        for (int s = 0; s < 2; ++s) {
            bf16x8 Br[4];
            #pragma unroll
            for (int r = 0; r < 4; ++r) {
                int pix = (wv * 2 + r) * 18 + r16 + kx;
                Br[r] = *reinterpret_cast<const bf16x8*>(
                    lds + ((pix * 128 + s * 64 + quad * 16) ^ ((pix & 7) << 4)));
            }
            #pragma unroll
            for (int ky = 0; ky < 3; ++ky) {
                int tap = ky * 3 + kx;
                bf16x8 A = *reinterpret_cast<const bf16x8*>(
                    wOe + (tap * 2 + s) * 512 + lane * 8);
                if ((tap ^ s) & 1) {
                    accO[0] = __builtin_amdgcn_mfma_f32_16x16x32_bf16(A, Br[ky],     accO[0], 0, 0, 0);
                    accO[1] = __builtin_amdgcn_mfma_f32_16x16x32_bf16(A, Br[ky + 1], accO[1], 0, 0, 0);
                } else {
                    accE[0] = __builtin_amdgcn_mfma_f32_16x16x32_bf16(A, Br[ky],     accE[0], 0, 0, 0);
                    accE[1] = __builtin_amdgcn_mfma_f32_16x16x32_bf16(A, Br[ky + 1], accE[1], 0, 0, 0);
                }
            }
        }
    }

    if (quad == 0) {
        float bias = ob[0];
        #pragma unroll
        for (int g = 0; g < 2; ++g) {
            int yg = y0 + wv * 2 + g;
            o[nb + (long)yg * W_ + x0 + r16] = accE[g][0] + accO[g][0] + bias;
        }
    }
}

extern "C" void kernel_launch(void* const* d_in, const int* in_sizes, int n_in,
                              void* d_out, int out_size, void* d_ws, size_t ws_size,
                              hipStream_t stream) {
    const float* low    = (const float*)d_in[0];
    const float* hsin   = (const float*)d_in[1];
    const float* imin   = (const float*)d_in[2];
    const float* dg1_w1 = (const float*)d_in[3];
    const float* dg1_s  = (const float*)d_in[4];
    const float* dg1_b  = (const float*)d_in[5];
    const float* dg1_m  = (const float*)d_in[6];
    const float* dg1_v  = (const float*)d_in[7];
    const float* dg1_w2 = (const float*)d_in[8];
    const float* dg2_w1 = (const float*)d_in[9];
    const float* dg2_s  = (const float*)d_in[10];
    const float* dg2_b  = (const float*)d_in[11];
    const float* dg2_m  = (const float*)d_in[12];
    const float* dg2_v  = (const float*)d_in[13];
    const float* dg2_w2 = (const float*)d_in[14];
    const float* gamma  = (const float*)d_in[15];
    const float* out_w  = (const float*)d_in[16];
    const float* out_b  = (const float*)d_in[17];

    float* ws    = (float*)d_ws;
    float* d1    = ws;                          // 2*PSZ_
    float* d2    = d1 + 2 * PSZ_;               // 2*PSZ_
    float* btap4 = d2 + 2 * PSZ_;               // 40
    unsigned short* wAe   = (unsigned short*)(btap4 + 40);   // 18432
    unsigned short* wOe   = wAe + 18432;        // 9216
    unsigned short* lowb  = wOe + 9216;         // FSZ_ bf16 NHWC
    unsigned short* highb = lowb + FSZ_;        // FSZ_ bf16 NHWC
    unsigned short* hsb   = highb + FSZ_;       // N*HH*WH*64 bf16 NHWC

    float* fout = (float*)d_out;                // FSZ_ (output 0, NCHW fp32)
    float* oout = fout + FSZ_;                  // PSZ_ (output 1)

    compose_w_kernel<<<36, 128, 0, stream>>>(
        dg1_w1, dg2_w1, dg1_s, dg1_b, dg1_m, dg1_v,
        dg2_s, dg2_b, dg2_m, dg2_v, dg1_w2, dg2_w2, out_w,
        wAe, wOe, btap4);
    nchw_to_nhwc_merged<<<1000, 256, 0, stream>>>(low, hsin, lowb, hsb);
    resize_high_nhwc<<<PSZ_ / 256, 256, 0, stream>>>(hsb, highb);
    d12_tiled_kernel<<<1600, 256, 0, stream>>>(
        lowb, highb, wAe, btap4, d1, d2);
    warp_out_fused<<<800, 512, 0, stream>>>(
        lowb, highb, d1, d2, imin, gamma, wOe, out_b, fout, oout);
}

// Round 23
// 114.064 us; speedup vs baseline: 1.1450x; 1.0505x over previous
//
#include <hip/hip_runtime.h>
#include <cmath>

#define N_   8
#define C_   64
#define H_   160
#define W_   160
#define HW_  25600
#define HH_  80
#define WH_  80
#define FSZ_ (N_ * C_ * HW_)   // 13,107,200
#define PSZ_ (N_ * HW_)        // 204,800

typedef unsigned short ushort8v __attribute__((ext_vector_type(8)));
typedef short          bf16x8  __attribute__((ext_vector_type(8)));
typedef float          f32x4   __attribute__((ext_vector_type(4)));

__device__ __forceinline__ float bf2f(unsigned short u) {
    return __uint_as_float(((unsigned)u) << 16);
}
__device__ __forceinline__ unsigned short f2bf(float f) {
    unsigned u = __float_as_uint(f);
    u += 0x7FFF + ((u >> 16) & 1);          // RNE
    return (unsigned short)(u >> 16);
}

// grid-sample setup: 4 tap indices + weights (align_corners=False, zeros pad)
__device__ __forceinline__ void gs_setup(float bgx, float bgy, float dx, float dy,
                                         int* idx, float* wgt)
{
    float px = ((bgx + dx * (1.f / 160.f)) + 1.f) * 80.f - 0.5f;
    float py = ((bgy + dy * (1.f / 160.f)) + 1.f) * 80.f - 0.5f;
    float x0f = floorf(px), y0f = floorf(py);
    float wx1 = px - x0f, wy1 = py - y0f, wx0 = 1.f - wx1, wy0 = 1.f - wy1;
    int x0 = (int)x0f, y0 = (int)y0f;
    float mx0 = ((unsigned)x0       < (unsigned)W_) ? 1.f : 0.f;
    float mx1 = ((unsigned)(x0 + 1) < (unsigned)W_) ? 1.f : 0.f;
    float my0 = ((unsigned)y0       < (unsigned)H_) ? 1.f : 0.f;
    float my1 = ((unsigned)(y0 + 1) < (unsigned)H_) ? 1.f : 0.f;
    int x0c = min(max(x0, 0), W_ - 1), x1c = min(max(x0 + 1, 0), W_ - 1);
    int y0c = min(max(y0, 0), H_ - 1), y1c = min(max(y0 + 1, 0), H_ - 1);
    idx[0] = y0c * W_ + x0c; wgt[0] = wy0 * wx0 * my0 * mx0;
    idx[1] = y0c * W_ + x1c; wgt[1] = wy0 * wx1 * my0 * mx1;
    idx[2] = y1c * W_ + x0c; wgt[2] = wy1 * wx0 * my1 * mx0;
    idx[3] = y1c * W_ + x1c; wgt[3] = wy1 * wx1 * my1 * mx1;
}

// -------- K1: merged prep: transpose (b<1000) + compose/pack (b>=1000) -----
__global__ __launch_bounds__(256) void prep_merged_kernel(
    const float* __restrict__ low, const float* __restrict__ hs,
    unsigned short* __restrict__ lowb, unsigned short* __restrict__ hsb,
    const float* __restrict__ w1a, const float* __restrict__ w1b,
    const float* __restrict__ s1, const float* __restrict__ b1,
    const float* __restrict__ m1, const float* __restrict__ v1,
    const float* __restrict__ s2, const float* __restrict__ b2,
    const float* __restrict__ m2, const float* __restrict__ v2,
    const float* __restrict__ w2a, const float* __restrict__ w2b,
    const float* __restrict__ ow,
    unsigned short* __restrict__ wAe, unsigned short* __restrict__ wOe,
    float* __restrict__ btap4)
{
    int b = blockIdx.x;                 // 1036: 800 low + 200 hs + 36 compose
    if (b < 1000) {
        const float* in;
        unsigned short* out;
        int hw, p;
        if (b < 800) { in = low; out = lowb; hw = HW_;       p = b * 256 + threadIdx.x; }
        else         { in = hs;  out = hsb;  hw = HH_ * WH_; p = (b - 800) * 256 + threadIdx.x; }
        int n = p / hw, rem = p % hw;
        const float* base = in + (long)n * 64 * hw + rem;
        unsigned o32[32];
        #pragma unroll
        for (int c2 = 0; c2 < 32; ++c2) {
            float v0 = base[(long)(2 * c2) * hw];
            float v1 = base[(long)(2 * c2 + 1) * hw];
            o32[c2] = (unsigned)f2bf(v0) | ((unsigned)f2bf(v1) << 16);
        }
        uint4* dst = reinterpret_cast<uint4*>(out + (long)p * 64);
        #pragma unroll
        for (int q = 0; q < 8; ++q)
            dst[q] = make_uint4(o32[q * 4], o32[q * 4 + 1], o32[q * 4 + 2], o32[q * 4 + 3]);
        return;
    }

    // ---- compose path (36 blocks, 128 active threads) ----
    __shared__ float ws2[64], bpart[64];
    int bId = b - 1000;          // 0..35
    int row = bId / 9, tap = bId % 9;
    int br = row >> 1, oc = row & 1;
    int tid = threadIdx.x;       // use 0..127 only

    const float* w1 = br ? w1b : w1a;
    const float* w2 = br ? w2b : w2a;

    if (tid < 64) {
        int mid = tid;
        float sc = br ? s2[mid] : s1[mid];
        float vv = br ? v2[mid] : v1[mid];
        float bb = br ? b2[mid] : b1[mid];
        float mm = br ? m2[mid] : m1[mid];
        float inv = sc * rsqrtf(vv + 1e-5f);
        float w2v = w2[oc * 576 + mid * 9 + tap];
        ws2[mid]   = w2v * inv;
        bpart[mid] = w2v * (bb - mm * inv);
    }
    __syncthreads();
    if (tid >= 128) return;

    float sum = 0.f;
    #pragma unroll 8
    for (int mid = 0; mid < 64; ++mid)
        sum = fmaf(ws2[mid], w1[mid * 128 + tid], sum);
    {
        int s = tid >> 5, g = (tid >> 3) & 3, j = tid & 7;
        wAe[(tap * 4 + s) * 512 + (row + 16 * g) * 8 + j] = f2bf(sum);
    }
    if (row == 0) {
        for (int i = tid; i < 1536; i += 128) {
            int j = i & 7, k = i >> 3;
            int s = k / 48, k48 = k % 48;
            int g = k48 / 12, r16v = 4 + (k48 % 12);
            wAe[(tap * 4 + s) * 512 + (r16v + 16 * g) * 8 + j] = 0;
        }
    }
    if (row == 1) {
        for (int i = tid; i < 1024; i += 128) {
            int j = i & 7, lane = (i >> 3) & 63, s = i >> 9;
            int rowl = lane & 15;
            int ci = s * 32 + ((lane >> 4) & 3) * 8 + j;
            float v = (rowl == 0) ? ow[ci * 9 + tap] : 0.f;
            wOe[(tap * 2 + s) * 512 + lane * 8 + j] = f2bf(v);
        }
    }
    if (tid < 64) {
        float part = bpart[tid];
        #pragma unroll
        for (int off = 32; off > 0; off >>= 1)
            part += __shfl_down(part, off);
        if (tid == 0) btap4[tap * 4 + row] = part;
    }
}

// -------- K2: bilinear resize 80->160 (align_corners=True) in NHWC bf16 -----
__global__ __launch_bounds__(256) void resize_high_nhwc(
    const unsigned short* __restrict__ hsb, unsigned short* __restrict__ highb)
{
    int p = blockIdx.x * 256 + threadIdx.x;
    int n = p / HW_, rem = p % HW_;
    int y = rem / W_, x = rem % W_;
    float sx = (x * 79.0f) / 159.0f;
    float sy = (y * 79.0f) / 159.0f;
    int ix0 = (int)sx, iy0 = (int)sy;
    float fx = sx - (float)ix0, fy = sy - (float)iy0;
    int ix1 = min(ix0 + 1, WH_ - 1), iy1 = min(iy0 + 1, HH_ - 1);
    long b = (long)n * (HH_ * WH_);
    const ushort8v* r00 = (const ushort8v*)(hsb + (b + iy0 * WH_ + ix0) * 64);
    const ushort8v* r01 = (const ushort8v*)(hsb + (b + iy0 * WH_ + ix1) * 64);
    const ushort8v* r10 = (const ushort8v*)(hsb + (b + iy1 * WH_ + ix0) * 64);
    const ushort8v* r11 = (const ushort8v*)(hsb + (b + iy1 * WH_ + ix1) * 64);
    float w00 = (1.f - fx) * (1.f - fy), w01 = fx * (1.f - fy);
    float w10 = (1.f - fx) * fy,         w11 = fx * fy;

    float acc[64];
    #pragma unroll
    for (int c = 0; c < 64; ++c) acc[c] = 0.f;
    #pragma unroll
    for (int q = 0; q < 8; ++q) {
        ushort8v v0 = r00[q], v1 = r01[q], v2 = r10[q], v3 = r11[q];
        #pragma unroll
        for (int j = 0; j < 8; ++j) {
            acc[q * 8 + j] = bf2f(v0[j]) * w00 + bf2f(v1[j]) * w01
                           + bf2f(v2[j]) * w10 + bf2f(v3[j]) * w11;
        }
    }
    unsigned o32[32];
    #pragma unroll
    for (int c2 = 0; c2 < 32; ++c2)
        o32[c2] = (unsigned)f2bf(acc[2 * c2]) | ((unsigned)f2bf(acc[2 * c2 + 1]) << 16);
    uint4* dst = reinterpret_cast<uint4*>(highb + (long)p * 64);
    #pragma unroll
    for (int q = 0; q < 8; ++q)
        dst[q] = make_uint4(o32[q * 4], o32[q * 4 + 1], o32[q * 4 + 2], o32[q * 4 + 3]);
}

// -------- K3: d1,d2 via COMPOSED conv3x3, LDS-tiled B + global A --------
__global__ __launch_bounds__(256) void d12_tiled_kernel(
    const unsigned short* __restrict__ lowb, const unsigned short* __restrict__ highb,
    const unsigned short* __restrict__ wAe, const float* __restrict__ btap4,
    float* __restrict__ d1, float* __restrict__ d2)
{
    __shared__ unsigned char lds[46080];   // 180 px * 256 B
    int b  = blockIdx.x;                  // 1600
    int n  = b / 200;
    int t  = b % 200;
    int ty = t / 10, tx = t % 10;         // 20 x 10 tiles of 8x16
    int y0 = ty * 8, x0 = tx * 16;
    int tid  = threadIdx.x;
    int lane = tid & 63;
    int wv   = tid >> 6;
    int r16  = lane & 15;
    int quad = lane >> 4;
    long nb = (long)n * HW_;

    for (int i = tid; i < 2880; i += 256) {
        int pix = i >> 4, qq = i & 15;
        int py = pix / 18, px = pix - py * 18;
        int gy = y0 + py - 1, gx = x0 + px - 1;
        bool valid = ((unsigned)gy < (unsigned)H_) && ((unsigned)gx < (unsigned)W_);
        ushort8v v = (ushort8v)0;
        if (valid) {
            const unsigned short* src = (qq < 8) ? lowb : highb;
            v = *reinterpret_cast<const ushort8v*>(
                src + ((long)(nb + gy * W_ + gx)) * 64 + (qq & 7) * 8);
        }
        *reinterpret_cast<ushort8v*>(
            lds + ((pix * 256 + qq * 16) ^ ((pix & 7) << 4))) = v;
    }
    __syncthreads();

    f32x4 accE[2], accO[2];
    accE[0] = accE[1] = accO[0] = accO[1] = (f32x4){0.f, 0.f, 0.f, 0.f};

    #pragma unroll
    for (int kx = 0; kx < 3; ++kx) {
        #pragma unroll
        for (int s = 0; s < 4; ++s) {
            bf16x8 Br[4];
            #pragma unroll
            for (int r = 0; r < 4; ++r) {
                int pix = (wv * 2 + r) * 18 + r16 + kx;
                Br[r] = *reinterpret_cast<const bf16x8*>(
                    lds + ((pix * 256 + s * 64 + quad * 16) ^ ((pix & 7) << 4)));
            }
            #pragma unroll
            for (int ky = 0; ky < 3; ++ky) {
                int tap = ky * 3 + kx;
                bf16x8 A = *reinterpret_cast<const bf16x8*>(
                    wAe + (tap * 4 + s) * 512 + lane * 8);
                if ((tap ^ s) & 1) {
                    accO[0] = __builtin_amdgcn_mfma_f32_16x16x32_bf16(A, Br[ky],     accO[0], 0, 0, 0);
                    accO[1] = __builtin_amdgcn_mfma_f32_16x16x32_bf16(A, Br[ky + 1], accO[1], 0, 0, 0);
                } else {
                    accE[0] = __builtin_amdgcn_mfma_f32_16x16x32_bf16(A, Br[ky],     accE[0], 0, 0, 0);
                    accE[1] = __builtin_amdgcn_mfma_f32_16x16x32_bf16(A, Br[ky + 1], accE[1], 0, 0, 0);
                }
            }
        }
    }

    #pragma unroll
    for (int g = 0; g < 2; ++g) {
        int yg = y0 + wv * 2 + g;
        int x  = x0 + r16;
        bool interior = (yg > 0) && (yg < H_ - 1) && (x0 > 0) && (x0 + 16 < W_);
        float b0 = 0.f, b1v = 0.f, b2v = 0.f, b3 = 0.f;
        #pragma unroll
        for (int tap = 0; tap < 9; ++tap) {
            int ky = tap / 3 - 1, kx = tap % 3 - 1;
            float m = 1.f;
            if (!interior) {
                int yy = yg + ky, xx = x + kx;
                m = (((unsigned)yy < (unsigned)H_) && ((unsigned)xx < (unsigned)W_))
                  ? 1.f : 0.f;
            }
            const float4 bt = *reinterpret_cast<const float4*>(btap4 + tap * 4);
            b0  = fmaf(m, bt.x, b0);
            b1v = fmaf(m, bt.y, b1v);
            b2v = fmaf(m, bt.z, b2v);
            b3  = fmaf(m, bt.w, b3);
        }
        if (quad == 0) {
            long p = nb + (long)yg * W_ + x;
            *reinterpret_cast<float2*>(d1 + p * 2) =
                make_float2(accE[g][0] + accO[g][0] + b0,
                            accE[g][1] + accO[g][1] + b1v);
            *reinterpret_cast<float2*>(d2 + p * 2) =
                make_float2(accE[g][2] + accO[g][2] + b2v,
                            accE[g][3] + accO[g][3] + b3);
        }
    }
}

// -------- K4: FUSED warp+combine -> f + LDS, then out conv3x3 via MFMA ------
// Tile 16x16 output, halo 18x18 = 324 px. 512 threads (8 waves).
__global__ __launch_bounds__(512) void warp_out_fused(
    const unsigned short* __restrict__ lowb, const unsigned short* __restrict__ highb,
    const float* __restrict__ d1, const float* __restrict__ d2,
    const float* __restrict__ imin, const float* __restrict__ gamma,
    const unsigned short* __restrict__ wOe, const float* __restrict__ ob,
    float* __restrict__ f, float* __restrict__ o)
{
    __shared__ unsigned char lds[41472];   // 324 px * 128 B
    int b  = blockIdx.x;                  // 800
    int n  = b / 100;
    int t  = b % 100;
    int ty = t / 10, tx = t % 10;
    int y0 = ty * 16, x0 = tx * 16;
    int tid  = threadIdx.x;
    long nb = (long)n * HW_;
    float gm = gamma[0];

    // ---- phase 1: 1296 units (324 px x 4 quarters) ----
    for (int u = tid; u < 1296; u += 512) {
        int pix = u >> 2, quarter = u & 3;
        int py = pix / 18, px = pix - py * 18;
        int gy = y0 + py - 1, gx = x0 + px - 1;
        bool valid = ((unsigned)gy < (unsigned)H_) && ((unsigned)gx < (unsigned)W_);

        unsigned o32[8];
        #pragma unroll
        for (int k = 0; k < 8; ++k) o32[k] = 0;

        if (valid) {
            int pp = gy * W_ + gx;
            long p = nb + pp;

            float bgx = -1.f + gx * (2.f / 159.f);
            float bgy = -1.f + gy * (2.f / 159.f);
            float2 dv1 = *reinterpret_cast<const float2*>(d1 + p * 2);
            float2 dv2 = *reinterpret_cast<const float2*>(d2 + p * 2);

            int idx1[4], idx2[4];
            float wgt1[4], wgt2[4];
            gs_setup(bgx, bgy, dv1.x, dv1.y, idx1, wgt1);
            gs_setup(bgx, bgy, dv2.x, dv2.y, idx2, wgt2);

            float s;
            {
                float sx = (gx * 79.0f) / 159.0f;
                float sy = (gy * 79.0f) / 159.0f;
                int ix0 = (int)sx, iy0 = (int)sy;
                float fx = sx - (float)ix0, fy = sy - (float)iy0;
                int ix1 = min(ix0 + 1, WH_ - 1), iy1 = min(iy0 + 1, HH_ - 1);
                const float* ip = imin + n * (HH_ * WH_);
                float v00 = ip[iy0 * WH_ + ix0], v01 = ip[iy0 * WH_ + ix1];
                float v10 = ip[iy1 * WH_ + ix0], v11 = ip[iy1 * WH_ + ix1];
                float v = (v00 * (1.f - fx) + v01 * fx) * (1.f - fy)
                        + (v10 * (1.f - fx) + v11 * fx) * fy;
                s = 1.f + gm * (1.f / (1.f + expf(-v)));
            }

            float acc[16];
            #pragma unroll
            for (int c = 0; c < 16; ++c) acc[c] = 0.f;

            #pragma unroll
            for (int j = 0; j < 4; ++j) {
                const ushort8v* row = (const ushort8v*)(
                    highb + (nb + idx1[j]) * 64 + quarter * 16);
                float w = wgt1[j];
                #pragma unroll
                for (int q = 0; q < 2; ++q) {
                    ushort8v v = row[q];
                    #pragma unroll
                    for (int k = 0; k < 8; ++k)
                        acc[q * 8 + k] = fmaf(bf2f(v[k]), w, acc[q * 8 + k]);
                }
            }
            #pragma unroll
            for (int j = 0; j < 4; ++j) {
                const ushort8v* row = (const ushort8v*)(
                    lowb + (nb + idx2[j]) * 64 + quarter * 16);
                float w = wgt2[j];
                #pragma unroll
                for (int q = 0; q < 2; ++q) {
                    ushort8v v = row[q];
                    #pragma unroll
                    for (int k = 0; k < 8; ++k)
                        acc[q * 8 + k] = fmaf(bf2f(v[k]), w, acc[q * 8 + k]);
                }
            }

            bool interior = (py >= 1) && (py <= 16) && (px >= 1) && (px <= 16);
            float* fp = f + ((long)n * 64 + quarter * 16) * HW_ + pp;
            #pragma unroll
            for (int c2 = 0; c2 < 8; ++c2) {
                float f0 = acc[2 * c2]     * s;
                float f1 = acc[2 * c2 + 1] * s;
                if (interior) {
                    fp[(long)(2 * c2) * HW_]     = f0;
                    fp[(long)(2 * c2 + 1) * HW_] = f1;
                }
                o32[c2] = (unsigned)f2bf(f0) | ((unsigned)f2bf(f1) << 16);
            }
        }

        int base = pix * 128 + quarter * 32;
        int sw   = (pix & 7) << 4;
        *reinterpret_cast<uint4*>(lds + ((base) ^ sw)) =
            make_uint4(o32[0], o32[1], o32[2], o32[3]);
        *reinterpret_cast<uint4*>(lds + ((base + 16) ^ sw)) =
            make_uint4(o32[4], o32[5], o32[6], o32[7]);
    }
    __syncthreads();

    // ---- phase 2: out conv via MFMA; wave wv owns rows 2wv, 2wv+1 ----
    int lane = tid & 63;
    int wv   = tid >> 6;
    int r16  = lane & 15;
    int quad = lane >> 4;

    f32x4 accE[2], accO[2];
    accE[0] = accE[1] = accO[0] = accO[1] = (f32x4){0.f, 0.f, 0.f, 0.f};

    #pragma unroll
    for (int kx = 0; kx < 3; ++kx) {
        #pragma unroll
        for (int s = 0; s < 2; ++s) {
            bf16x8 Br[4];
            #pragma unroll
            for (int r = 0; r < 4; ++r) {
                int pix = (wv * 2 + r) * 18 + r16 + kx;
                Br[r] = *reinterpret_cast<const bf16x8*>(
                    lds + ((pix * 128 + s * 64 + quad * 16) ^ ((pix & 7) << 4)));
            }
            #pragma unroll
            for (int ky = 0; ky < 3; ++ky) {
                int tap = ky * 3 + kx;
                bf16x8 A = *reinterpret_cast<const bf16x8*>(
                    wOe + (tap * 2 + s) * 512 + lane * 8);
                if ((tap ^ s) & 1) {
                    accO[0] = __builtin_amdgcn_mfma_f32_16x16x32_bf16(A, Br[ky],     accO[0], 0, 0, 0);
                    accO[1] = __builtin_amdgcn_mfma_f32_16x16x32_bf16(A, Br[ky + 1], accO[1], 0, 0, 0);
                } else {
                    accE[0] = __builtin_amdgcn_mfma_f32_16x16x32_bf16(A, Br[ky],     accE[0], 0, 0, 0);
                    accE[1] = __builtin_amdgcn_mfma_f32_16x16x32_bf16(A, Br[ky + 1], accE[1], 0, 0, 0);
                }
            }
        }
    }

    if (quad == 0) {
        float bias = ob[0];
        #pragma unroll
        for (int g = 0; g < 2; ++g) {
            int yg = y0 + wv * 2 + g;
            o[nb + (long)yg * W_ + x0 + r16] = accE[g][0] + accO[g][0] + bias;
        }
    }
}

extern "C" void kernel_launch(void* const* d_in, const int* in_sizes, int n_in,
                              void* d_out, int out_size, void* d_ws, size_t ws_size,
                              hipStream_t stream) {
    const float* low    = (const float*)d_in[0];
    const float* hsin   = (const float*)d_in[1];
    const float* imin   = (const float*)d_in[2];
    const float* dg1_w1 = (const float*)d_in[3];
    const float* dg1_s  = (const float*)d_in[4];
    const float* dg1_b  = (const float*)d_in[5];
    const float* dg1_m  = (const float*)d_in[6];
    const float* dg1_v  = (const float*)d_in[7];
    const float* dg1_w2 = (const float*)d_in[8];
    const float* dg2_w1 = (const float*)d_in[9];
    const float* dg2_s  = (const float*)d_in[10];
    const float* dg2_b  = (const float*)d_in[11];
    const float* dg2_m  = (const float*)d_in[12];
    const float* dg2_v  = (const float*)d_in[13];
    const float* dg2_w2 = (const float*)d_in[14];
    const float* gamma  = (const float*)d_in[15];
    const float* out_w  = (const float*)d_in[16];
    const float* out_b  = (const float*)d_in[17];

    float* ws    = (float*)d_ws;
    float* d1    = ws;                          // 2*PSZ_
    float* d2    = d1 + 2 * PSZ_;               // 2*PSZ_
    float* btap4 = d2 + 2 * PSZ_;               // 40
    unsigned short* wAe   = (unsigned short*)(btap4 + 40);   // 18432
    unsigned short* wOe   = wAe + 18432;        // 9216
    unsigned short* lowb  = wOe + 9216;         // FSZ_ bf16 NHWC
    unsigned short* highb = lowb + FSZ_;        // FSZ_ bf16 NHWC
    unsigned short* hsb   = highb + FSZ_;       // N*HH*WH*64 bf16 NHWC

    float* fout = (float*)d_out;                // FSZ_ (output 0, NCHW fp32)
    float* oout = fout + FSZ_;                  // PSZ_ (output 1)

    prep_merged_kernel<<<1036, 256, 0, stream>>>(
        low, hsin, lowb, hsb,
        dg1_w1, dg2_w1, dg1_s, dg1_b, dg1_m, dg1_v,
        dg2_s, dg2_b, dg2_m, dg2_v, dg1_w2, dg2_w2, out_w,
        wAe, wOe, btap4);
    resize_high_nhwc<<<PSZ_ / 256, 256, 0, stream>>>(hsb, highb);
    d12_tiled_kernel<<<1600, 256, 0, stream>>>(
        lowb, highb, wAe, btap4, d1, d2);
    warp_out_fused<<<800, 512, 0, stream>>>(
        lowb, highb, d1, d2, imin, gamma, wOe, out_b, fout, oout);
}